// Round 1
// baseline (245.640 us; speedup 1.0000x reference)
//
#include <hip/hip_runtime.h>

#define N_IMG 256
#define H_IMG 512
#define W_IMG 512

__device__ __forceinline__ int mirror_idx(int idx, int n) {
    // match jnp: period = 2*(n-1); m = mod(idx, period) (non-negative); if m>=n: period-m
    const int p = 2 * (n - 1);
    int m = idx % p;
    if (m < 0) m += p;
    return (m >= n) ? (p - m) : m;
}

__global__ __launch_bounds__(128) void FluxPosRegressor_shift_kernel(
    const float* __restrict__ imgs,
    const float* __restrict__ flux,
    const float* __restrict__ noise,
    const float* __restrict__ dxdy,
    float* __restrict__ out)
{
    const int n   = blockIdx.z;
    const int row = blockIdx.y;
    const int tid = threadIdx.x;

    const float dx = dxdy[2 * n + 0];
    const float dy = dxdy[2 * n + 1];
    const float fl = flux[n];
    const float no = noise[n];

    // row interpolation coords (match reference f32 arithmetic exactly)
    const float rf  = (float)row + dy;
    const float r0f = floorf(rf);
    const float tr  = rf - r0f;
    const int   r0  = (int)r0f;
    const int   mr0 = mirror_idx(r0,     H_IMG);
    const int   mr1 = mirror_idx(r0 + 1, H_IMG);

    const float* __restrict__ row0 = imgs + ((size_t)n * H_IMG + mr0) * W_IMG;
    const float* __restrict__ row1 = imgs + ((size_t)n * H_IMG + mr1) * W_IMG;
    float* __restrict__ orow       = out  + ((size_t)n * H_IMG + row) * W_IMG;

    const int c_base = tid * 4;

    float4 res;
    float* rp = &res.x;
#pragma unroll
    for (int j = 0; j < 4; ++j) {
        const int   col = c_base + j;
        const float cf  = (float)col + dx;
        const float c0f = floorf(cf);
        const float tc  = cf - c0f;
        const int   c0  = (int)c0f;
        const int   mc0 = mirror_idx(c0,     W_IMG);
        const int   mc1 = mirror_idx(c0 + 1, W_IMG);

        const float g00 = row0[mc0];
        const float g01 = row0[mc1];
        const float g10 = row1[mc0];
        const float g11 = row1[mc1];

        const float top = (1.0f - tc) * g00 + tc * g01;
        const float bot = (1.0f - tc) * g10 + tc * g11;
        const float v   = (1.0f - tr) * top + tr * bot;
        rp[j] = fmaf(v, fl, no);
    }

    *reinterpret_cast<float4*>(orow + c_base) = res;
}

extern "C" void kernel_launch(void* const* d_in, const int* in_sizes, int n_in,
                              void* d_out, int out_size, void* d_ws, size_t ws_size,
                              hipStream_t stream) {
    const float* imgs  = (const float*)d_in[0];
    const float* flux  = (const float*)d_in[1];
    const float* noise = (const float*)d_in[2];
    const float* dxdy  = (const float*)d_in[3];
    float* out = (float*)d_out;

    dim3 block(128, 1, 1);                    // 128 threads * 4 cols = 512 = W
    dim3 grid(W_IMG / (4 * 128), H_IMG, N_IMG);  // (1, 512, 256)
    FluxPosRegressor_shift_kernel<<<grid, block, 0, stream>>>(imgs, flux, noise, dxdy, out);
}

// Round 2
// 125.455 us; speedup vs baseline: 1.9580x; 1.9580x over previous
//
#include <hip/hip_runtime.h>

#define N_IMG 256
#define H_IMG 512
#define W_IMG 512

__device__ __forceinline__ int mirror_idx(int idx, int n) {
    // match jnp: period = 2*(n-1); m = mod(idx, period) (non-negative); if m>=n: period-m
    const int p = 2 * (n - 1);
    int m = idx % p;
    if (m < 0) m += p;
    return (m >= n) ? (p - m) : m;
}

__global__ __launch_bounds__(128) void FluxPosRegressor_shift_kernel(
    const float* __restrict__ imgs,
    const float* __restrict__ flux,
    const float* __restrict__ noise,
    const float* __restrict__ dxdy,
    float* __restrict__ out)
{
    const int n   = blockIdx.z;
    const int row = blockIdx.y;
    const int tid = threadIdx.x;

    const float dx = dxdy[2 * n + 0];
    const float dy = dxdy[2 * n + 1];
    const float fl = flux[n];
    const float no = noise[n];

    // row interpolation coords (match reference f32 arithmetic exactly)
    const float rf  = (float)row + dy;
    const float r0f = floorf(rf);
    const float tr  = rf - r0f;
    const int   r0  = (int)r0f;
    const int   mr0 = mirror_idx(r0,     H_IMG);
    const int   mr1 = mirror_idx(r0 + 1, H_IMG);

    const float* __restrict__ row0 = imgs + ((size_t)n * H_IMG + mr0) * W_IMG;
    const float* __restrict__ row1 = imgs + ((size_t)n * H_IMG + mr1) * W_IMG;
    float* __restrict__ orow       = out  + ((size_t)n * H_IMG + row) * W_IMG;

    const int P = 2 * (W_IMG - 1);  // 1022

#pragma unroll
    for (int k = 0; k < 4; ++k) {
        const int   col = tid + k * 128;       // strided: lane-stride 4B -> coalesced
        const float cf  = (float)col + dx;
        const float c0f = floorf(cf);
        const float tc  = cf - c0f;
        const int   c0  = (int)c0f;

        // one mod, derive both mirrored taps
        int m = c0 % P;
        if (m < 0) m += P;
        const int mc0 = (m >= W_IMG) ? (P - m) : m;
        int m1 = m + 1;
        m1 = (m1 == P) ? 0 : m1;
        const int mc1 = (m1 >= W_IMG) ? (P - m1) : m1;

        const float g00 = row0[mc0];
        const float g01 = row0[mc1];
        const float g10 = row1[mc0];
        const float g11 = row1[mc1];

        const float top = (1.0f - tc) * g00 + tc * g01;
        const float bot = (1.0f - tc) * g10 + tc * g11;
        const float v   = (1.0f - tr) * top + tr * bot;
        orow[col] = fmaf(v, fl, no);
    }
}

extern "C" void kernel_launch(void* const* d_in, const int* in_sizes, int n_in,
                              void* d_out, int out_size, void* d_ws, size_t ws_size,
                              hipStream_t stream) {
    const float* imgs  = (const float*)d_in[0];
    const float* flux  = (const float*)d_in[1];
    const float* noise = (const float*)d_in[2];
    const float* dxdy  = (const float*)d_in[3];
    float* out = (float*)d_out;

    dim3 block(128, 1, 1);
    dim3 grid(1, H_IMG, N_IMG);   // one block per output row
    FluxPosRegressor_shift_kernel<<<grid, block, 0, stream>>>(imgs, flux, noise, dxdy, out);
}

// Round 3
// 122.164 us; speedup vs baseline: 2.0107x; 1.0269x over previous
//
#include <hip/hip_runtime.h>

#define N_IMG 256
#define H_IMG 512
#define W_IMG 512

// mirror for idx in [-P, P] without integer division.
// jnp semantics: m = mod(idx, P) (non-negative), then m>=n ? P-m : m.
// For |idx| <= P this is: m = idx<0 ? idx+P : idx;  (idx==P -> m==P -> P-m==0 ok)
__device__ __forceinline__ int mirror_small(int idx, int n, int P) {
    int m = idx;
    if (m < 0) m += P;
    return (m >= n) ? (P - m) : m;
}

__global__ __launch_bounds__(128) void FluxPosRegressor_shift_kernel(
    const float* __restrict__ imgs,
    const float* __restrict__ flux,
    const float* __restrict__ noise,
    const float* __restrict__ dxdy,
    float* __restrict__ out)
{
    const int n   = blockIdx.z;
    const int row = blockIdx.y;
    const int tid = threadIdx.x;

    const float dx = dxdy[2 * n + 0];
    const float dy = dxdy[2 * n + 1];
    const float fl = flux[n];
    const float no = noise[n];

    // row interpolation coords (match reference f32 arithmetic exactly)
    const float rf  = (float)row + dy;
    const float r0f = floorf(rf);
    const float tr  = rf - r0f;
    const int   r0  = (int)r0f;
    const int   PH  = 2 * (H_IMG - 1);
    const int   mr0 = mirror_small(r0,     H_IMG, PH);
    const int   mr1 = mirror_small(r0 + 1, H_IMG, PH);

    const float* __restrict__ row0 = imgs + ((size_t)n * H_IMG + mr0) * W_IMG;
    const float* __restrict__ row1 = imgs + ((size_t)n * H_IMG + mr1) * W_IMG;
    float* __restrict__ orow       = out  + ((size_t)n * H_IMG + row) * W_IMG;

    const int PW = 2 * (W_IMG - 1);  // 1022

#pragma unroll
    for (int k = 0; k < 4; ++k) {
        const int   col = tid + k * 128;       // strided: lane-stride 4B -> coalesced
        const float cf  = (float)col + dx;
        const float c0f = floorf(cf);
        const float tc  = cf - c0f;
        const int   c0  = (int)c0f;

        // |dx| << PW, so c0 in (-PW, PW): comparison-based mirror, no division
        int m = c0;
        if (m < 0) m += PW;
        const int mc0 = (m >= W_IMG) ? (PW - m) : m;
        int m1 = m + 1;                        // m in [0,PW) -> m1 in [1,PW]
        const int mc1 = (m1 >= W_IMG) ? (PW - m1) : m1;

        const float g00 = row0[mc0];
        const float g01 = row0[mc1];
        const float g10 = row1[mc0];
        const float g11 = row1[mc1];

        const float top = (1.0f - tc) * g00 + tc * g01;
        const float bot = (1.0f - tc) * g10 + tc * g11;
        const float v   = (1.0f - tr) * top + tr * bot;
        __builtin_nontemporal_store(fmaf(v, fl, no), &orow[col]);
    }
}

extern "C" void kernel_launch(void* const* d_in, const int* in_sizes, int n_in,
                              void* d_out, int out_size, void* d_ws, size_t ws_size,
                              hipStream_t stream) {
    const float* imgs  = (const float*)d_in[0];
    const float* flux  = (const float*)d_in[1];
    const float* noise = (const float*)d_in[2];
    const float* dxdy  = (const float*)d_in[3];
    float* out = (float*)d_out;

    dim3 block(128, 1, 1);
    dim3 grid(1, H_IMG, N_IMG);   // one block per output row
    FluxPosRegressor_shift_kernel<<<grid, block, 0, stream>>>(imgs, flux, noise, dxdy, out);
}